// Round 7
// baseline (967.150 us; speedup 1.0000x reference)
//
#include <hip/hip_runtime.h>
#include <hip/hip_fp8.h>

typedef __bf16 bf16_t;
typedef __bf16 bf16x8 __attribute__((ext_vector_type(8)));
typedef float floatx16 __attribute__((ext_vector_type(16)));
typedef unsigned long long u64;

#define B_ 16
#define N_ 4096
#define K_ 32

// ws layout (bytes):
//   idx   u16 [16][4096][32]         @ 0        (4194304)
//   g_enc u32 [16][1024]             @ 4194304  (65536)
//   w3f8  fp8 frag-major [131072]    @ 4259840  (131072)
//   w2sw  bf16 frag-major [8192]     @ 4390912  (16384)
//   tmat  f32 [16][9]                @ 4407296  (576)

__device__ __forceinline__ unsigned enc_f(float f) {
    unsigned u = __float_as_uint(f);
    return (u & 0x80000000u) ? ~u : (u | 0x80000000u);
}
__device__ __forceinline__ float dec_f(unsigned e) {
    return __uint_as_float((e & 0x80000000u) ? (e & 0x7fffffffu) : ~e);
}
// dequant 8 fp8-e4m3 bytes -> bf16x8
__device__ __forceinline__ bf16x8 dq8(u64 v) {
    bf16x8 o;
    #pragma unroll
    for (int i = 0; i < 8; i++) {
        __hip_fp8_e4m3 t; t.__x = (unsigned char)(v >> (8 * i));
        o[i] = (bf16_t)(float)t;
    }
    return o;
}

// ---------------------------------------------------------------------------
// K1: kNN top-32 (unchanged from round 5). 8 threads/query, register top-12,
// med3-chain insert, 8-way LDS tournament merge. grid 1024 x 512.
// Side jobs: zero g_enc, build fp8 frag-major w3f8 + bf16 frag-major w2sw.
// ---------------------------------------------------------------------------
__global__ __launch_bounds__(512, 4) void knn_kernel(
    const float* __restrict__ x, const float* __restrict__ w3,
    const float* __restrict__ w2, unsigned short* __restrict__ idxb,
    unsigned* __restrict__ g_enc, unsigned char* __restrict__ w3f8,
    bf16_t* __restrict__ w2sw)
{
    __shared__ __align__(16) float4 cand[8 * 513];   // 65664 B
    unsigned* lists = (unsigned*)cand;               // reused after scan
    const int tid = threadIdx.x;
    const int bid = blockIdx.x;  // 1024 blocks

    // side jobs.  w3f8 byte o: jj=o&7, half=(o>>3)&1, l=(o>>4)&63,
    // kp=(o>>10)&3, cb=o>>12; ks=kp*2+half, lm=l&31, hi=l>>5;
    // value = fp8(w3[cb*32+lm][ks*16+hi*8+jj]).
    {
        const int g = bid * 512 + tid;
        if (g < 131072) {
            const int jj = g & 7, half = (g >> 3) & 1, lI = (g >> 4) & 63;
            const int kp = (g >> 10) & 3, cb = g >> 12;
            const int ks = kp * 2 + half, lmI = lI & 31, hiI = lI >> 5;
            __hip_fp8_e4m3 t(w3[(cb * 32 + lmI) * 128 + ks * 16 + hiI * 8 + jj]);
            w3f8[g] = t.__x;
        } else if (g < 139264) {
            const int o = g - 131072;
            const int f = o >> 9, r = o & 511, lI = r >> 3, jj = r & 7;
            const int ks = f & 3, nb = f >> 2, lmI = lI & 31, hiI = lI >> 5;
            w2sw[o] = (bf16_t)w2[(nb * 32 + lmI) * 64 + ks * 16 + hiI * 8 + jj];
        } else if (g < 155648) {
            g_enc[g - 139264] = 0u;
        }
    }

    const int b  = bid >> 6;                    // 64 blocks per batch
    const int q  = tid >> 3;                    // local query 0..63
    const int n  = (bid & 63) * 64 + q;         // global query index
    const int t  = tid & 7;                     // candidate chunk
    const float* xb = x + b * 3 * N_;

    for (int j = tid; j < N_; j += 512) {
        float cx = xb[j], cy = xb[N_ + j], cz = xb[2 * N_ + j];
        cand[j + (j >> 9)] = make_float4(-2.f * cx, -2.f * cy, -2.f * cz,
                                         fmaf(cx, cx, fmaf(cy, cy, cz * cz)));
    }
    __syncthreads();

    const float xi0 = xb[n], xi1 = xb[N_ + n], xi2 = xb[2 * N_ + n];
    const float xisq = fmaf(xi0, xi0, fmaf(xi1, xi1, xi2 * xi2));

    unsigned r[12];
    #pragma unroll
    for (int s = 0; s < 12; s++) r[s] = 0x7F7FFFFFu;   // FLT_MAX sentinel

    const int j0 = t * 512;
    const int pb = t * 513;
    #pragma unroll 4
    for (int jj = 0; jj < 512; jj++) {
        const float4 c = cand[pb + jj];
        const float d = fmaf(c.z, xi2, fmaf(c.y, xi1, fmaf(c.x, xi0, c.w)));
        const float df = fmaxf(d + xisq, 0.f);
        const unsigned key = (__float_as_uint(df) & 0xFFFFF000u) | (unsigned)(j0 + jj);
        #pragma unroll
        for (int s = 11; s >= 1; s--) {
            const unsigned hv = r[s - 1] > key ? r[s - 1] : key;
            r[s] = r[s] < hv ? r[s] : hv;           // med3
        }
        r[0] = r[0] < key ? r[0] : key;
    }
    __syncthreads();   // cand reads done; reuse LDS for lists

    #pragma unroll
    for (int k = 0; k < 12; k++) lists[tid * 13 + k] = r[k];   // stride 13: conflict-free
    __syncthreads();

    if (tid < 64) {
        #define LRD(i, p) lists[(tid * 8 + (i)) * 13 + (p)]
        unsigned h0 = LRD(0, 0), h1 = LRD(1, 0), h2 = LRD(2, 0), h3 = LRD(3, 0);
        unsigned h4 = LRD(4, 0), h5 = LRD(5, 0), h6 = LRD(6, 0), h7 = LRD(7, 0);
        int p0 = 0, p1 = 0, p2 = 0, p3 = 0, p4 = 0, p5 = 0, p6 = 0, p7 = 0;
        const int nq = (bid & 63) * 64 + tid;
        unsigned short* op = idxb + ((size_t)(b * N_ + nq)) * K_;
        #pragma unroll 1
        for (int k = 0; k < K_; k++) {
            unsigned m01 = h0 < h1 ? h0 : h1, m23 = h2 < h3 ? h2 : h3;
            unsigned m45 = h4 < h5 ? h4 : h5, m67 = h6 < h7 ? h6 : h7;
            unsigned ma = m01 < m23 ? m01 : m23, mb = m45 < m67 ? m45 : m67;
            const unsigned v = ma < mb ? ma : mb;
            op[k] = (unsigned short)(v & 0xFFFu);
            if (v == h0) { p0++; h0 = p0 < 12 ? LRD(0, p0) : 0xFFFFFFFFu; }
            else if (v == h1) { p1++; h1 = p1 < 12 ? LRD(1, p1) : 0xFFFFFFFFu; }
            else if (v == h2) { p2++; h2 = p2 < 12 ? LRD(2, p2) : 0xFFFFFFFFu; }
            else if (v == h3) { p3++; h3 = p3 < 12 ? LRD(3, p3) : 0xFFFFFFFFu; }
            else if (v == h4) { p4++; h4 = p4 < 12 ? LRD(4, p4) : 0xFFFFFFFFu; }
            else if (v == h5) { p5++; h5 = p5 < 12 ? LRD(5, p5) : 0xFFFFFFFFu; }
            else if (v == h6) { p6++; h6 = p6 < 12 ? LRD(6, p6) : 0xFFFFFFFFu; }
            else              { p7++; h7 = p7 < 12 ? LRD(7, p7) : 0xFFFFFFFFu; }
        }
        #undef LRD
    }
}

// ---------------------------------------------------------------------------
// K2: fused edge MLP.  Round-5 structure (launch_bounds(256,2), no spills,
// full 64 KB bf16 h2l, a3 held in regs) with three changes:
//  (1) w3 streamed as fp8 (half the L1/B bytes), dequantized to bf16 in VALU
//      right before the bf16 MFMA (separate pipe; overlaps matrix work);
//  (2) depth-5 tree max epilogue (short dep chain);
//  (3) raw s_barrier per chunk to lockstep the 4 waves for L1 reuse.
// ---------------------------------------------------------------------------
__global__ __launch_bounds__(256, 2) void mlp_kernel(
    const float* __restrict__ x, const unsigned short* __restrict__ idxb,
    const float* __restrict__ w1, const float* __restrict__ b1,
    const float* __restrict__ b2,
    const bf16_t* __restrict__ w2sw, const unsigned char* __restrict__ w3f8,
    unsigned* __restrict__ g_enc)
{
    __shared__ __align__(16) bf16_t h2l[256 * 128];   // 65536 B, swizzled
    __shared__ unsigned gl[1024];                     // 4096 B
    __shared__ __align__(16) float4 w1l[64];          // 1024 B

    const int tid = threadIdx.x;
    const int b   = blockIdx.x >> 9;          // 512 blocks per batch
    const int p0  = (blockIdx.x & 511) * 8;   // first point
    const float* xb = x + b * 3 * N_;

    const int wv = tid >> 6;
    const int l  = tid & 63;
    const int lm = l & 31;
    const int hi = l >> 5;

    for (int i = tid; i < 1024; i += 256) gl[i] = 0u;
    if (tid < 64)
        w1l[tid] = make_float4(w1[tid * 3], w1[tid * 3 + 1], w1[tid * 3 + 2], b1[tid]);
    __syncthreads();

    // ---- layer 1 (VALU) -> A1 frags ----
    bf16x8 a1[2][4];   // [mt][ks]; A[m=lm][k=ks*16+hi*8+jj]
    float d0[2], d1[2], d2[2];
    #pragma unroll
    for (int mt = 0; mt < 2; mt++) {
        const int pp = p0 + wv * 2 + mt;                 // wave-uniform
        const int j  = idxb[((size_t)(b * N_ + pp)) * K_ + lm];
        d0[mt] = xb[j]          - xb[pp];
        d1[mt] = xb[N_ + j]     - xb[N_ + pp];
        d2[mt] = xb[2 * N_ + j] - xb[2 * N_ + pp];
    }
    #pragma unroll
    for (int ks = 0; ks < 4; ks++)
        #pragma unroll
        for (int jj = 0; jj < 8; jj++) {
            const float4 w = w1l[ks * 16 + hi * 8 + jj];
            #pragma unroll
            for (int mt = 0; mt < 2; mt++)
                a1[mt][ks][jj] = (bf16_t)fmaxf(
                    fmaf(w.z, d2[mt], fmaf(w.y, d1[mt], fmaf(w.x, d0[mt], w.w))), 0.f);
        }

    // ---- layer 2 (MFMA 32x32x16, K=64), 2x2 (np,nt) passes, low reg peak ----
    #pragma unroll
    for (int np = 0; np < 2; np++)
        #pragma unroll
        for (int nt = 0; nt < 2; nt++) {
            floatx16 acc2[2];
            acc2[0] = (floatx16)0.f; acc2[1] = (floatx16)0.f;
            #pragma unroll
            for (int ks = 0; ks < 4; ks++) {
                const bf16x8 bw2 = *(const bf16x8*)&w2sw[(((np * 2 + nt) * 4 + ks) * 64 + l) * 8];
                acc2[0] = __builtin_amdgcn_mfma_f32_32x32x16_bf16(a1[0][ks], bw2, acc2[0], 0, 0, 0);
                acc2[1] = __builtin_amdgcn_mfma_f32_32x32x16_bf16(a1[1][ks], bw2, acc2[1], 0, 0, 0);
            }
            const int col = np * 64 + nt * 32 + lm;
            const float bias = b2[col];
            const int c = col >> 3, ci = col & 7;
            #pragma unroll
            for (int mt = 0; mt < 2; mt++)
                #pragma unroll
                for (int reg = 0; reg < 16; reg++) {
                    const int row = wv * 64 + mt * 32 + (reg & 3) + 8 * (reg >> 2) + 4 * hi;
                    h2l[row * 128 + (c ^ (row & 15)) * 8 + ci] =
                        (bf16_t)fmaxf(acc2[mt][reg] + bias, 0.f);
                }
        }

    // ---- A3 frags: load once (own-wave rows; in-wave lgkm ordering) ----
    bf16x8 a3[2][8];   // [mt][ks]
    #pragma unroll
    for (int mt = 0; mt < 2; mt++)
        #pragma unroll
        for (int ks = 0; ks < 8; ks++) {
            const int R = wv * 64 + mt * 32 + lm;
            const int c = ks * 2 + hi;
            a3[mt][ks] = *(const bf16x8*)&h2l[R * 128 + (c ^ (R & 15)) * 8];
        }

    // ---- layer 3: 32 chunks of 32 channels; fp8 B double-buffered in regs,
    //      dequant->bf16 in VALU, per-chunk s_barrier for L1 lockstep ----
    const uint4* w3v = (const uint4*)w3f8;   // 16 B = 2 frags (kp pairing)
    u64 bwA[8], bwB[8];
    #pragma unroll
    for (int kp = 0; kp < 4; kp++) {
        const uint4 v = w3v[kp * 64 + l];
        bwA[2 * kp]     = ((u64)v.y << 32) | v.x;
        bwA[2 * kp + 1] = ((u64)v.w << 32) | v.z;
    }

    #pragma unroll 1
    for (int cc = 0; cc < 16; cc++) {
        #pragma unroll
        for (int half = 0; half < 2; half++) {
            const int cb = cc * 2 + half;
            u64* cur = half ? bwB : bwA;
            u64* nxt = half ? bwA : bwB;
            if (cb < 31) {
                #pragma unroll
                for (int kp = 0; kp < 4; kp++) {
                    const uint4 v = w3v[((cb + 1) * 4 + kp) * 64 + l];
                    nxt[2 * kp]     = ((u64)v.y << 32) | v.x;
                    nxt[2 * kp + 1] = ((u64)v.w << 32) | v.z;
                }
            }
            floatx16 acc3[2];
            acc3[0] = (floatx16)0.f; acc3[1] = (floatx16)0.f;
            #pragma unroll
            for (int ks = 0; ks < 8; ks++) {
                const bf16x8 bwb = dq8(cur[ks]);
                acc3[0] = __builtin_amdgcn_mfma_f32_32x32x16_bf16(a3[0][ks], bwb, acc3[0], 0, 0, 0);
                acc3[1] = __builtin_amdgcn_mfma_f32_32x32x16_bf16(a3[1][ks], bwb, acc3[1], 0, 0, 0);
            }
            // depth-5 parallel max tree
            float t16[16];
            #pragma unroll
            for (int i = 0; i < 16; i++) t16[i] = fmaxf(acc3[0][i], acc3[1][i]);
            float t8[8];
            #pragma unroll
            for (int i = 0; i < 8; i++) t8[i] = fmaxf(t16[i], t16[i + 8]);
            float t4[4];
            #pragma unroll
            for (int i = 0; i < 4; i++) t4[i] = fmaxf(t8[i], t8[i + 4]);
            float m = fmaxf(fmaxf(t4[0], t4[1]), fmaxf(t4[2], t4[3]));
            m = fmaxf(m, __shfl_xor(m, 32));
            if (hi == 0) atomicMax(&gl[cb * 32 + lm], enc_f(m));
            __builtin_amdgcn_s_barrier();   // align waves (no memory drain)
        }
    }

    __syncthreads();
    for (int i = tid; i < 1024; i += 256)
        atomicMax(&g_enc[b * 1024 + i], gl[i]);
}

// ---------------------------------------------------------------------------
// K3: FC head per batch. grid 16 x 256.
// ---------------------------------------------------------------------------
__global__ __launch_bounds__(256) void head_kernel(
    const unsigned* __restrict__ g_enc, const float* __restrict__ b3,
    const float* __restrict__ fw1, const float* __restrict__ fb1,
    const float* __restrict__ fw2, const float* __restrict__ fb2,
    const float* __restrict__ fw3, const float* __restrict__ fb3,
    float* __restrict__ tmat)
{
    __shared__ __align__(16) float g[1024];
    __shared__ __align__(16) float f1[512];
    __shared__ __align__(16) float f2[256];
    const int t = threadIdx.x, b = blockIdx.x;

    for (int i = t; i < 1024; i += 256)
        g[i] = fmaxf(dec_f(g_enc[b * 1024 + i]) + b3[i], 0.f);
    __syncthreads();

    for (int o = t; o < 512; o += 256) {
        const float4* wr = (const float4*)(fw1 + (size_t)o * 1024);
        const float4* gv = (const float4*)g;
        float acc = fb1[o];
        for (int i = 0; i < 256; i++) {
            float4 a = wr[i], c = gv[i];
            acc = fmaf(a.x, c.x, acc); acc = fmaf(a.y, c.y, acc);
            acc = fmaf(a.z, c.z, acc); acc = fmaf(a.w, c.w, acc);
        }
        f1[o] = fmaxf(acc, 0.f);
    }
    __syncthreads();
    {
        const int o = t;
        const float4* wr = (const float4*)(fw2 + (size_t)o * 512);
        const float4* fv = (const float4*)f1;
        float acc = fb2[o];
        for (int i = 0; i < 128; i++) {
            float4 a = wr[i], c = fv[i];
            acc = fmaf(a.x, c.x, acc); acc = fmaf(a.y, c.y, acc);
            acc = fmaf(a.z, c.z, acc); acc = fmaf(a.w, c.w, acc);
        }
        f2[o] = fmaxf(acc, 0.f);
    }
    __syncthreads();
    if (t < 9) {
        const float4* wr = (const float4*)(fw3 + (size_t)t * 256);
        const float4* fv = (const float4*)f2;
        float acc = fb3[t];
        for (int i = 0; i < 64; i++) {
            float4 a = wr[i], c = fv[i];
            acc = fmaf(a.x, c.x, acc); acc = fmaf(a.y, c.y, acc);
            acc = fmaf(a.z, c.z, acc); acc = fmaf(a.w, c.w, acc);
        }
        if (t == 0 || t == 4 || t == 8) acc += 1.f;
        tmat[b * 9 + t] = acc;
    }
}

// ---------------------------------------------------------------------------
// K4: out[b][d][n] = sum_c x[b][c][n] * t[b][c][d].  grid 256 x 256.
// ---------------------------------------------------------------------------
__global__ __launch_bounds__(256) void out_kernel(
    const float* __restrict__ x, const float* __restrict__ tmat,
    float* __restrict__ out)
{
    const int gid = blockIdx.x * 256 + threadIdx.x;
    const int b = gid >> 12, n = gid & 4095;
    const float* T = tmat + b * 9;
    const float x0 = x[b * 12288 + n];
    const float x1 = x[b * 12288 + 4096 + n];
    const float x2 = x[b * 12288 + 8192 + n];
    #pragma unroll
    for (int d = 0; d < 3; d++)
        out[b * 12288 + d * 4096 + n] =
            fmaf(x2, T[6 + d], fmaf(x1, T[3 + d], x0 * T[d]));
}

extern "C" void kernel_launch(void* const* d_in, const int* in_sizes, int n_in,
                              void* d_out, int out_size, void* d_ws, size_t ws_size,
                              hipStream_t stream) {
    const float* x   = (const float*)d_in[0];
    const float* w1  = (const float*)d_in[1];
    const float* b1  = (const float*)d_in[2];
    const float* w2  = (const float*)d_in[3];
    const float* b2  = (const float*)d_in[4];
    const float* w3  = (const float*)d_in[5];
    const float* b3  = (const float*)d_in[6];
    const float* fw1 = (const float*)d_in[7];
    const float* fb1 = (const float*)d_in[8];
    const float* fw2 = (const float*)d_in[9];
    const float* fb2 = (const float*)d_in[10];
    const float* fw3 = (const float*)d_in[11];
    const float* fb3 = (const float*)d_in[12];
    float* out = (float*)d_out;

    char* ws = (char*)d_ws;
    unsigned short* idxb = (unsigned short*)ws;
    unsigned* g_enc = (unsigned*)(ws + 4194304);
    unsigned char* w3f8 = (unsigned char*)(ws + 4259840);
    bf16_t* w2sw = (bf16_t*)(ws + 4390912);
    float* tmat  = (float*)(ws + 4407296);

    knn_kernel<<<1024, 512, 0, stream>>>(x, w3, w2, idxb, g_enc, w3f8, w2sw);
    mlp_kernel<<<8192, 256, 0, stream>>>(x, idxb, w1, b1, b2, w2sw, w3f8, g_enc);
    head_kernel<<<16, 256, 0, stream>>>(g_enc, b3, fw1, fb1, fw2, fb2, fw3, fb3, tmat);
    out_kernel<<<256, 256, 0, stream>>>(x, tmat, out);
}

// Round 8
// 785.978 us; speedup vs baseline: 1.2305x; 1.2305x over previous
//
#include <hip/hip_runtime.h>
#include <hip/hip_fp8.h>

typedef __bf16 bf16_t;
typedef __bf16 bf16x8 __attribute__((ext_vector_type(8)));
typedef float floatx16 __attribute__((ext_vector_type(16)));
typedef unsigned long long u64;

#define B_ 16
#define N_ 4096
#define K_ 32

// ws layout (bytes):
//   idx   u16 [16][4096][32]         @ 0        (4194304)
//   g_enc u32 [16][1024]             @ 4194304  (65536)
//   w3f8  fp8 frag-major [131072]    @ 4259840  (131072)   (= w3 * 16)
//   w2sw  bf16 frag-major [8192]     @ 4390912  (16384)
//   tmat  f32 [16][9]                @ 4407296  (576)

__device__ __forceinline__ unsigned enc_f(float f) {
    unsigned u = __float_as_uint(f);
    return (u & 0x80000000u) ? ~u : (u | 0x80000000u);
}
__device__ __forceinline__ float dec_f(unsigned e) {
    return __uint_as_float((e & 0x80000000u) ? (e & 0x7fffffffu) : ~e);
}

// ---------------------------------------------------------------------------
// K1: kNN top-32 (unchanged core). 8 threads/query, register top-12,
// med3-chain insert, 8-way LDS tournament merge. grid 1024 x 512.
// Side jobs: zero g_enc, build fp8 frag-major w3f8 (x16) + bf16 w2sw.
// ---------------------------------------------------------------------------
__global__ __launch_bounds__(512, 4) void knn_kernel(
    const float* __restrict__ x, const float* __restrict__ w3,
    const float* __restrict__ w2, unsigned short* __restrict__ idxb,
    unsigned* __restrict__ g_enc, unsigned char* __restrict__ w3f8,
    bf16_t* __restrict__ w2sw)
{
    __shared__ __align__(16) float4 cand[8 * 513];   // 65664 B
    unsigned* lists = (unsigned*)cand;               // reused after scan
    const int tid = threadIdx.x;
    const int bid = blockIdx.x;  // 1024 blocks

    // side jobs.  w3f8 byte o: jj=o&7, half=(o>>3)&1, l=(o>>4)&63,
    // kp=(o>>10)&3, cb=o>>12; ks=kp*2+half, lm=l&31, hi=l>>5;
    // value = fp8(16 * w3[cb*32+lm][ks*16+hi*8+jj]).
    {
        const int g = bid * 512 + tid;
        if (g < 131072) {
            const int jj = g & 7, half = (g >> 3) & 1, lI = (g >> 4) & 63;
            const int kp = (g >> 10) & 3, cb = g >> 12;
            const int ks = kp * 2 + half, lmI = lI & 31, hiI = lI >> 5;
            __hip_fp8_e4m3 t(16.0f * w3[(cb * 32 + lmI) * 128 + ks * 16 + hiI * 8 + jj]);
            w3f8[g] = t.__x;
        } else if (g < 139264) {
            const int o = g - 131072;
            const int f = o >> 9, r = o & 511, lI = r >> 3, jj = r & 7;
            const int ks = f & 3, nb = f >> 2, lmI = lI & 31, hiI = lI >> 5;
            w2sw[o] = (bf16_t)w2[(nb * 32 + lmI) * 64 + ks * 16 + hiI * 8 + jj];
        } else if (g < 155648) {
            g_enc[g - 139264] = 0u;
        }
    }

    const int b  = bid >> 6;                    // 64 blocks per batch
    const int q  = tid >> 3;                    // local query 0..63
    const int n  = (bid & 63) * 64 + q;         // global query index
    const int t  = tid & 7;                     // candidate chunk
    const float* xb = x + b * 3 * N_;

    for (int j = tid; j < N_; j += 512) {
        float cx = xb[j], cy = xb[N_ + j], cz = xb[2 * N_ + j];
        cand[j + (j >> 9)] = make_float4(-2.f * cx, -2.f * cy, -2.f * cz,
                                         fmaf(cx, cx, fmaf(cy, cy, cz * cz)));
    }
    __syncthreads();

    const float xi0 = xb[n], xi1 = xb[N_ + n], xi2 = xb[2 * N_ + n];
    const float xisq = fmaf(xi0, xi0, fmaf(xi1, xi1, xi2 * xi2));

    unsigned r[12];
    #pragma unroll
    for (int s = 0; s < 12; s++) r[s] = 0x7F7FFFFFu;   // FLT_MAX sentinel

    const int j0 = t * 512;
    const int pb = t * 513;
    #pragma unroll 4
    for (int jj = 0; jj < 512; jj++) {
        const float4 c = cand[pb + jj];
        const float d = fmaf(c.z, xi2, fmaf(c.y, xi1, fmaf(c.x, xi0, c.w)));
        const float df = fmaxf(d + xisq, 0.f);
        const unsigned key = (__float_as_uint(df) & 0xFFFFF000u) | (unsigned)(j0 + jj);
        #pragma unroll
        for (int s = 11; s >= 1; s--) {
            const unsigned hv = r[s - 1] > key ? r[s - 1] : key;
            r[s] = r[s] < hv ? r[s] : hv;           // med3
        }
        r[0] = r[0] < key ? r[0] : key;
    }
    __syncthreads();   // cand reads done; reuse LDS for lists

    #pragma unroll
    for (int k = 0; k < 12; k++) lists[tid * 13 + k] = r[k];   // stride 13: conflict-free
    __syncthreads();

    if (tid < 64) {
        #define LRD(i, p) lists[(tid * 8 + (i)) * 13 + (p)]
        unsigned h0 = LRD(0, 0), h1 = LRD(1, 0), h2 = LRD(2, 0), h3 = LRD(3, 0);
        unsigned h4 = LRD(4, 0), h5 = LRD(5, 0), h6 = LRD(6, 0), h7 = LRD(7, 0);
        int p0 = 0, p1 = 0, p2 = 0, p3 = 0, p4 = 0, p5 = 0, p6 = 0, p7 = 0;
        const int nq = (bid & 63) * 64 + tid;
        unsigned short* op = idxb + ((size_t)(b * N_ + nq)) * K_;
        #pragma unroll 1
        for (int k = 0; k < K_; k++) {
            unsigned m01 = h0 < h1 ? h0 : h1, m23 = h2 < h3 ? h2 : h3;
            unsigned m45 = h4 < h5 ? h4 : h5, m67 = h6 < h7 ? h6 : h7;
            unsigned ma = m01 < m23 ? m01 : m23, mb = m45 < m67 ? m45 : m67;
            const unsigned v = ma < mb ? ma : mb;
            op[k] = (unsigned short)(v & 0xFFFu);
            if (v == h0) { p0++; h0 = p0 < 12 ? LRD(0, p0) : 0xFFFFFFFFu; }
            else if (v == h1) { p1++; h1 = p1 < 12 ? LRD(1, p1) : 0xFFFFFFFFu; }
            else if (v == h2) { p2++; h2 = p2 < 12 ? LRD(2, p2) : 0xFFFFFFFFu; }
            else if (v == h3) { p3++; h3 = p3 < 12 ? LRD(3, p3) : 0xFFFFFFFFu; }
            else if (v == h4) { p4++; h4 = p4 < 12 ? LRD(4, p4) : 0xFFFFFFFFu; }
            else if (v == h5) { p5++; h5 = p5 < 12 ? LRD(5, p5) : 0xFFFFFFFFu; }
            else if (v == h6) { p6++; h6 = p6 < 12 ? LRD(6, p6) : 0xFFFFFFFFu; }
            else              { p7++; h7 = p7 < 12 ? LRD(7, p7) : 0xFFFFFFFFu; }
        }
        #undef LRD
    }
}

// ---------------------------------------------------------------------------
// K2: fused edge MLP.  Round-5 structure (launch_bounds(256,2), no spills,
// barrier-free layer 3, a3 held in regs) with layer 3 on fp8 MFMA:
// h2 stored as fp8 (x256) in LDS, w3 streamed as fp8 (x16) from L2 —
// half the L1 B-bytes and LDS A-bytes, same MFMA count, ZERO dequant VALU.
// Column-max scaled back by 1/4096 before encoding.
// ---------------------------------------------------------------------------
__global__ __launch_bounds__(256, 2) void mlp_kernel(
    const float* __restrict__ x, const unsigned short* __restrict__ idxb,
    const float* __restrict__ w1, const float* __restrict__ b1,
    const float* __restrict__ b2,
    const bf16_t* __restrict__ w2sw, const unsigned char* __restrict__ w3f8,
    unsigned* __restrict__ g_enc)
{
    __shared__ __align__(16) unsigned char h2l[256 * 128];  // 32768 B, fp8, swizzled
    __shared__ unsigned gl[1024];                           // 4096 B
    __shared__ __align__(16) float4 w1l[64];                // 1024 B

    const int tid = threadIdx.x;
    const int b   = blockIdx.x >> 9;          // 512 blocks per batch
    const int p0  = (blockIdx.x & 511) * 8;   // first point
    const float* xb = x + b * 3 * N_;

    const int wv = tid >> 6;
    const int l  = tid & 63;
    const int lm = l & 31;
    const int hi = l >> 5;

    for (int i = tid; i < 1024; i += 256) gl[i] = 0u;
    if (tid < 64)
        w1l[tid] = make_float4(w1[tid * 3], w1[tid * 3 + 1], w1[tid * 3 + 2], b1[tid]);
    __syncthreads();

    // ---- layer 1 (VALU) -> A1 frags (bf16) ----
    bf16x8 a1[2][4];   // [mt][ks]; A[m=lm][k=ks*16+hi*8+jj]
    float d0[2], d1[2], d2[2];
    #pragma unroll
    for (int mt = 0; mt < 2; mt++) {
        const int pp = p0 + wv * 2 + mt;                 // wave-uniform
        const int j  = idxb[((size_t)(b * N_ + pp)) * K_ + lm];
        d0[mt] = xb[j]          - xb[pp];
        d1[mt] = xb[N_ + j]     - xb[N_ + pp];
        d2[mt] = xb[2 * N_ + j] - xb[2 * N_ + pp];
    }
    #pragma unroll
    for (int ks = 0; ks < 4; ks++)
        #pragma unroll
        for (int jj = 0; jj < 8; jj++) {
            const float4 w = w1l[ks * 16 + hi * 8 + jj];
            #pragma unroll
            for (int mt = 0; mt < 2; mt++)
                a1[mt][ks][jj] = (bf16_t)fmaxf(
                    fmaf(w.z, d2[mt], fmaf(w.y, d1[mt], fmaf(w.x, d0[mt], w.w))), 0.f);
        }

    // ---- layer 2 (MFMA 32x32x16 bf16), 2x2 (np,nt) passes; epilogue
    //      quantizes h2*256 to fp8 into swizzled LDS (8-byte granules) ----
    #pragma unroll
    for (int np = 0; np < 2; np++)
        #pragma unroll
        for (int nt = 0; nt < 2; nt++) {
            floatx16 acc2[2];
            acc2[0] = (floatx16)0.f; acc2[1] = (floatx16)0.f;
            #pragma unroll
            for (int ks = 0; ks < 4; ks++) {
                const bf16x8 bw2 = *(const bf16x8*)&w2sw[(((np * 2 + nt) * 4 + ks) * 64 + l) * 8];
                acc2[0] = __builtin_amdgcn_mfma_f32_32x32x16_bf16(a1[0][ks], bw2, acc2[0], 0, 0, 0);
                acc2[1] = __builtin_amdgcn_mfma_f32_32x32x16_bf16(a1[1][ks], bw2, acc2[1], 0, 0, 0);
            }
            const int col = np * 64 + nt * 32 + lm;
            const float bias = b2[col];
            const int gcol = col >> 3, cb7 = col & 7;
            #pragma unroll
            for (int mt = 0; mt < 2; mt++)
                #pragma unroll
                for (int reg = 0; reg < 16; reg++) {
                    const int row = wv * 64 + mt * 32 + (reg & 3) + 8 * (reg >> 2) + 4 * hi;
                    __hip_fp8_e4m3 t(fmaxf(acc2[mt][reg] + bias, 0.f) * 256.0f);
                    h2l[row * 128 + ((gcol ^ (row & 15)) << 3) + cb7] = t.__x;
                }
        }

    // ---- A3 frags (fp8, 8 B/lane): load once, hold for all 32 chunks ----
    u64 a3[2][8];   // [mt][ks]; A[m=lm][k=ks*16+hi*8+jj]
    #pragma unroll
    for (int mt = 0; mt < 2; mt++)
        #pragma unroll
        for (int ks = 0; ks < 8; ks++) {
            const int R = wv * 64 + mt * 32 + lm;
            const int g = ks * 2 + hi;
            a3[mt][ks] = *(const u64*)&h2l[R * 128 + ((g ^ (R & 15)) << 3)];
        }

    // ---- layer 3: 32 chunks of 32 channels; fp8 MFMA, B double-buffered
    //      in regs from coalesced L2 stream, NO barriers, no dequant ----
    const uint4* w3v = (const uint4*)w3f8;   // 16 B = 2 frags (ks pair)
    u64 bwA[8], bwB[8];
    #pragma unroll
    for (int kp = 0; kp < 4; kp++) {
        const uint4 v = w3v[kp * 64 + l];
        bwA[2 * kp]     = ((u64)v.y << 32) | v.x;
        bwA[2 * kp + 1] = ((u64)v.w << 32) | v.z;
    }

    #pragma unroll 1
    for (int cc = 0; cc < 16; cc++) {
        #pragma unroll
        for (int half = 0; half < 2; half++) {
            const int cb = cc * 2 + half;
            u64* cur = half ? bwB : bwA;
            u64* nxt = half ? bwA : bwB;
            if (cb < 31) {
                #pragma unroll
                for (int kp = 0; kp < 4; kp++) {
                    const uint4 v = w3v[((cb + 1) * 4 + kp) * 64 + l];
                    nxt[2 * kp]     = ((u64)v.y << 32) | v.x;
                    nxt[2 * kp + 1] = ((u64)v.w << 32) | v.z;
                }
            }
            floatx16 acc3[2];
            acc3[0] = (floatx16)0.f; acc3[1] = (floatx16)0.f;
            #pragma unroll
            for (int ks = 0; ks < 8; ks++) {
                acc3[0] = __builtin_amdgcn_mfma_f32_32x32x16_fp8_fp8(
                    (long long)a3[0][ks], (long long)cur[ks], acc3[0], 0, 0, 0);
                acc3[1] = __builtin_amdgcn_mfma_f32_32x32x16_fp8_fp8(
                    (long long)a3[1][ks], (long long)cur[ks], acc3[1], 0, 0, 0);
            }
            // depth-5 parallel max tree, then undo the 256*16 scaling
            float t16[16];
            #pragma unroll
            for (int i = 0; i < 16; i++) t16[i] = fmaxf(acc3[0][i], acc3[1][i]);
            float t8[8];
            #pragma unroll
            for (int i = 0; i < 8; i++) t8[i] = fmaxf(t16[i], t16[i + 8]);
            float t4[4];
            #pragma unroll
            for (int i = 0; i < 4; i++) t4[i] = fmaxf(t8[i], t8[i + 4]);
            float m = fmaxf(fmaxf(t4[0], t4[1]), fmaxf(t4[2], t4[3]));
            m = fmaxf(m, __shfl_xor(m, 32)) * 2.44140625e-4f;   // 1/4096
            if (hi == 0) atomicMax(&gl[cb * 32 + lm], enc_f(m));
        }
    }

    __syncthreads();
    for (int i = tid; i < 1024; i += 256)
        atomicMax(&g_enc[b * 1024 + i], gl[i]);
}

// ---------------------------------------------------------------------------
// K3: FC head per batch. grid 16 x 256.
// ---------------------------------------------------------------------------
__global__ __launch_bounds__(256) void head_kernel(
    const unsigned* __restrict__ g_enc, const float* __restrict__ b3,
    const float* __restrict__ fw1, const float* __restrict__ fb1,
    const float* __restrict__ fw2, const float* __restrict__ fb2,
    const float* __restrict__ fw3, const float* __restrict__ fb3,
    float* __restrict__ tmat)
{
    __shared__ __align__(16) float g[1024];
    __shared__ __align__(16) float f1[512];
    __shared__ __align__(16) float f2[256];
    const int t = threadIdx.x, b = blockIdx.x;

    for (int i = t; i < 1024; i += 256)
        g[i] = fmaxf(dec_f(g_enc[b * 1024 + i]) + b3[i], 0.f);
    __syncthreads();

    for (int o = t; o < 512; o += 256) {
        const float4* wr = (const float4*)(fw1 + (size_t)o * 1024);
        const float4* gv = (const float4*)g;
        float acc = fb1[o];
        for (int i = 0; i < 256; i++) {
            float4 a = wr[i], c = gv[i];
            acc = fmaf(a.x, c.x, acc); acc = fmaf(a.y, c.y, acc);
            acc = fmaf(a.z, c.z, acc); acc = fmaf(a.w, c.w, acc);
        }
        f1[o] = fmaxf(acc, 0.f);
    }
    __syncthreads();
    {
        const int o = t;
        const float4* wr = (const float4*)(fw2 + (size_t)o * 512);
        const float4* fv = (const float4*)f1;
        float acc = fb2[o];
        for (int i = 0; i < 128; i++) {
            float4 a = wr[i], c = fv[i];
            acc = fmaf(a.x, c.x, acc); acc = fmaf(a.y, c.y, acc);
            acc = fmaf(a.z, c.z, acc); acc = fmaf(a.w, c.w, acc);
        }
        f2[o] = fmaxf(acc, 0.f);
    }
    __syncthreads();
    if (t < 9) {
        const float4* wr = (const float4*)(fw3 + (size_t)t * 256);
        const float4* fv = (const float4*)f2;
        float acc = fb3[t];
        for (int i = 0; i < 64; i++) {
            float4 a = wr[i], c = fv[i];
            acc = fmaf(a.x, c.x, acc); acc = fmaf(a.y, c.y, acc);
            acc = fmaf(a.z, c.z, acc); acc = fmaf(a.w, c.w, acc);
        }
        if (t == 0 || t == 4 || t == 8) acc += 1.f;
        tmat[b * 9 + t] = acc;
    }
}

// ---------------------------------------------------------------------------
// K4: out[b][d][n] = sum_c x[b][c][n] * t[b][c][d].  grid 256 x 256.
// ---------------------------------------------------------------------------
__global__ __launch_bounds__(256) void out_kernel(
    const float* __restrict__ x, const float* __restrict__ tmat,
    float* __restrict__ out)
{
    const int gid = blockIdx.x * 256 + threadIdx.x;
    const int b = gid >> 12, n = gid & 4095;
    const float* T = tmat + b * 9;
    const float x0 = x[b * 12288 + n];
    const float x1 = x[b * 12288 + 4096 + n];
    const float x2 = x[b * 12288 + 8192 + n];
    #pragma unroll
    for (int d = 0; d < 3; d++)
        out[b * 12288 + d * 4096 + n] =
            fmaf(x2, T[6 + d], fmaf(x1, T[3 + d], x0 * T[d]));
}

extern "C" void kernel_launch(void* const* d_in, const int* in_sizes, int n_in,
                              void* d_out, int out_size, void* d_ws, size_t ws_size,
                              hipStream_t stream) {
    const float* x   = (const float*)d_in[0];
    const float* w1  = (const float*)d_in[1];
    const float* b1  = (const float*)d_in[2];
    const float* w2  = (const float*)d_in[3];
    const float* b2  = (const float*)d_in[4];
    const float* w3  = (const float*)d_in[5];
    const float* b3  = (const float*)d_in[6];
    const float* fw1 = (const float*)d_in[7];
    const float* fb1 = (const float*)d_in[8];
    const float* fw2 = (const float*)d_in[9];
    const float* fb2 = (const float*)d_in[10];
    const float* fw3 = (const float*)d_in[11];
    const float* fb3 = (const float*)d_in[12];
    float* out = (float*)d_out;

    char* ws = (char*)d_ws;
    unsigned short* idxb = (unsigned short*)ws;
    unsigned* g_enc = (unsigned*)(ws + 4194304);
    unsigned char* w3f8 = (unsigned char*)(ws + 4259840);
    bf16_t* w2sw = (bf16_t*)(ws + 4390912);
    float* tmat  = (float*)(ws + 4407296);

    knn_kernel<<<1024, 512, 0, stream>>>(x, w3, w2, idxb, g_enc, w3f8, w2sw);
    mlp_kernel<<<8192, 256, 0, stream>>>(x, idxb, w1, b1, b2, w2sw, w3f8, g_enc);
    head_kernel<<<16, 256, 0, stream>>>(g_enc, b3, fw1, fb1, fw2, fb2, fw3, fb3, tmat);
    out_kernel<<<256, 256, 0, stream>>>(x, tmat, out);
}